// Round 1
// baseline (102.731 us; speedup 1.0000x reference)
//
#include <hip/hip_runtime.h>

constexpr int NL = 32;    // layers
constexpr int PPT = 4;    // points per thread (4 -> 8 waves/SIMD full occupancy)

// State is tracked scaled by c = 2*log2(e) so that e^{2p} = 2^(P) is a bare
// v_exp_f32. All affine table constants are pre-scaled by c in build_tables.
#define C_SCALE 2.8853900817779268f    // 2*log2(e)
#define INV_C   0.34657359027997264f   // ln(2)/2

__device__ __forceinline__ float fast_exp2(float x) {
#if __has_builtin(__builtin_amdgcn_exp2f)
    return __builtin_amdgcn_exp2f(x);
#else
    return __expf(0.69314718055994531f * x);   // fallback: exp(x*ln2)
#endif
}

// Table layout per layer i (16 floats = 4 float4 rows):
//  row0 [0..3]   forward:  m00,m01,m10,m11
//  row1 [4..7]   forward:  C0,C1,T,0        (T = -2*c*aw; aw-const folded into C)
//  row2 [8..11]  inverse:  i00,i01,i10,i11
//  row3 [12..15] inverse:  D0,D1,U,0        (U = +2*c*aw; -aw-const folded into D)
__global__ void build_tables(const float* __restrict__ act_w,
                             const float* __restrict__ bias_b,
                             const float* __restrict__ lin_w,
                             float* __restrict__ tab)
{
    int t = threadIdx.x;
    if (t >= NL) return;
    // Compose the 8 unit shears into M (det = 1).
    float m00 = 1.f, m01 = 0.f, m10 = 0.f, m11 = 1.f;
    #pragma unroll
    for (int j = 0; j < 8; ++j) {
        float w = lin_w[t * 8 + j];
        if ((j & 1) == 0) { m00 = fmaf(w, m10, m00); m01 = fmaf(w, m11, m01); }
        else              { m10 = fmaf(w, m00, m10); m11 = fmaf(w, m01, m11); }
    }
    float b0 = bias_b[2 * t], b1 = bias_b[2 * t + 1];
    float aw = act_w[t];
    const float c = C_SCALE;
    float awc = aw * c;

    // Forward: activation (tanh add, with +awc folded forward through M), then
    // v <- M*(v + c*b).  C = c*M*b + awc*(M column of the activated coord).
    float C0 = c * fmaf(m00, b0, m01 * b1);
    float C1 = c * fmaf(m10, b0, m11 * b1);
    if ((t & 1) == 0) { C0 = fmaf(awc, m00, C0); C1 = fmaf(awc, m10, C1); } // act on q-row input p
    else              { C0 = fmaf(awc, m01, C0); C1 = fmaf(awc, m11, C1); } // act on p-row input q
    float* f = &tab[t * 16];
    f[0] = m00; f[1] = m01; f[2] = m10; f[3] = m11;
    f[4] = C0;  f[5] = C1;  f[6] = -2.f * awc; f[7] = 0.f;

    // Inverse: v <- Minv*v - c*b, then subtract activation (−awc folded into D).
    float i00 = m11, i01 = -m01, i10 = -m10, i11 = m00;
    float D0 = -c * b0, D1 = -c * b1;
    if ((t & 1) == 0) D0 -= awc; else D1 -= awc;
    // Fold the time-reversal p <- -p into the FIRST inverse layer (t == NL-1):
    // Minv * diag(1,-1) negates the second column. Sign folds are exact.
    if (t == NL - 1) { i01 = -i01; i11 = -i11; }
    f[8]  = i00; f[9]  = i01; f[10] = i10; f[11] = i11;
    f[12] = D0;  f[13] = D1;  f[14] = 2.f * awc; f[15] = 0.f;
}

__global__ __launch_bounds__(256, 8) void sympnet_main(
    const float* __restrict__ x,
    const float* __restrict__ tab,
    float* __restrict__ out)
{
    int gid = blockIdx.x * blockDim.x + threadIdx.x;
    int nthreads = gridDim.x * blockDim.x;
    const float4* x4 = (const float4*)x;
    float4* out4 = (float4*)out;
    const float4* t4 = (const float4*)tab;

    // Lane-consecutive layout: thread owns f4[gid] and f4[gid + nthreads]
    // -> every global load/store instruction is perfectly coalesced.
    float Q[PPT], P[PPT];
    {
        float4 v0 = x4[gid];
        float4 v1 = x4[gid + nthreads];
        Q[0] = C_SCALE * v0.x; P[0] = C_SCALE * v0.y;
        Q[1] = C_SCALE * v0.z; P[1] = C_SCALE * v0.w;
        Q[2] = C_SCALE * v1.x; P[2] = C_SCALE * v1.y;
        Q[3] = C_SCALE * v1.z; P[3] = C_SCALE * v1.w;
    }

    // ---------------- forward chain (2 layers / iter, tables double-buffered) ----------------
    {
        float4 fa = t4[0], fb = t4[1];       // even layer i   (act on q, tanh(p))
        float4 ga = t4[4], gb = t4[5];       // odd layer i+1  (act on p, tanh(q))
        #pragma unroll 1
        for (int i = 0; i < NL; i += 2) {
            int nx = (i + 2 < NL) ? (i + 2) : 0;          // wrapped prefetch (harmless)
            float4 nfa = t4[4 * nx],     nfb = t4[4 * nx + 1];
            float4 nga = t4[4 * nx + 4], ngb = t4[4 * nx + 5];
            #pragma unroll
            for (int k = 0; k < PPT; ++k) {
                float r  = __builtin_amdgcn_rcpf(fast_exp2(P[k]) + 1.0f);
                float Qa = fmaf(fb.z, r, Q[k]);
                float Qn = fmaf(fa.x, Qa, fmaf(fa.y, P[k], fb.x));
                float Pn = fmaf(fa.z, Qa, fmaf(fa.w, P[k], fb.y));
                float r2 = __builtin_amdgcn_rcpf(fast_exp2(Qn) + 1.0f);
                float Pa = fmaf(gb.z, r2, Pn);
                Q[k] = fmaf(ga.x, Qn, fmaf(ga.y, Pa, gb.x));
                P[k] = fmaf(ga.z, Qn, fmaf(ga.w, Pa, gb.y));
            }
            fa = nfa; fb = nfb; ga = nga; gb = ngb;
        }
    }

    // time reversal (P = -P) is folded into layer NL-1's inverse table.

    // ---------------- inverse chain (2 layers / iter, tables double-buffered) ----------------
    {
        int i = NL - 1;
        float4 ga = t4[4 * i + 2],       gb = t4[4 * i + 3];        // odd layer inverse
        float4 fa = t4[4 * (i - 1) + 2], fb = t4[4 * (i - 1) + 3];  // even layer inverse
        #pragma unroll 1
        for (; i > 0; i -= 2) {
            int nx = (i > 2) ? (i - 2) : (NL - 1);        // wrapped prefetch (harmless)
            float4 nga = t4[4 * nx + 2],       ngb = t4[4 * nx + 3];
            float4 nfa = t4[4 * (nx - 1) + 2], nfb = t4[4 * (nx - 1) + 3];
            #pragma unroll
            for (int k = 0; k < PPT; ++k) {
                float Qn = fmaf(ga.x, Q[k], fmaf(ga.y, P[k], gb.x));
                float Pn = fmaf(ga.z, Q[k], fmaf(ga.w, P[k], gb.y));
                float r  = __builtin_amdgcn_rcpf(fast_exp2(Qn) + 1.0f);
                Pn = fmaf(gb.z, r, Pn);
                float Q2 = fmaf(fa.x, Qn, fmaf(fa.y, Pn, fb.x));
                float P2 = fmaf(fa.z, Qn, fmaf(fa.w, Pn, fb.y));
                float r2 = __builtin_amdgcn_rcpf(fast_exp2(P2) + 1.0f);
                Q[k] = fmaf(fb.z, r2, Q2);
                P[k] = P2;
            }
            ga = nga; gb = ngb; fa = nfa; fb = nfb;
        }
    }

    // final scale [1, -1] and unscale by 1/c
    {
        float4 o0, o1;
        o0.x =  INV_C * Q[0];  o0.y = -INV_C * P[0];
        o0.z =  INV_C * Q[1];  o0.w = -INV_C * P[1];
        o1.x =  INV_C * Q[2];  o1.y = -INV_C * P[2];
        o1.z =  INV_C * Q[3];  o1.w = -INV_C * P[3];
        out4[gid] = o0;
        out4[gid + nthreads] = o1;
    }
}

extern "C" void kernel_launch(void* const* d_in, const int* in_sizes, int n_in,
                              void* d_out, int out_size, void* d_ws, size_t ws_size,
                              hipStream_t stream) {
    const float* x      = (const float*)d_in[0];
    const float* act_w  = (const float*)d_in[1];
    const float* bias_b = (const float*)d_in[2];
    const float* lin_w  = (const float*)d_in[3];
    float* out = (float*)d_out;
    float* tab = (float*)d_ws;   // NL*16 floats = 2 KB

    build_tables<<<1, 64, 0, stream>>>(act_w, bias_b, lin_w, tab);

    int npts = in_sizes[0] / 2;                    // 2097152
    int nthreads = npts / PPT;                     // 524288
    int blocks = (nthreads + 255) / 256;           // 2048
    sympnet_main<<<blocks, 256, 0, stream>>>(x, tab, out);
}

// Round 2
// 102.371 us; speedup vs baseline: 1.0035x; 1.0035x over previous
//
#include <hip/hip_runtime.h>

constexpr int NL = 32;    // layers
constexpr int PPT = 4;    // points per thread (4 -> 8 waves/SIMD full occupancy)

// State is tracked scaled by c = 2*log2(e) so that e^{2p} = 2^(P) is a bare
// v_exp_f32. All affine table constants are pre-scaled by c.
#define C_SCALE 2.8853900817779268f    // 2*log2(e)
#define INV_C   0.34657359027997264f   // ln(2)/2

__device__ __forceinline__ float fast_exp2(float x) {
#if __has_builtin(__builtin_amdgcn_exp2f)
    return __builtin_amdgcn_exp2f(x);
#else
    return __expf(0.69314718055994531f * x);   // fallback: exp(x*ln2)
#endif
}

// Table layout per layer i (16 floats = 4 float4 rows), built in LDS per block:
//  row0 [0..3]   forward:  m00,m01,m10,m11
//  row1 [4..7]   forward:  C0,C1,T,0        (T = -2*c*aw; aw-const folded into C)
//  row2 [8..11]  inverse:  i00,i01,i10,i11  (time-reversal folded into layer NL-1)
//  row3 [12..15] inverse:  D0,D1,U,0        (U = +2*c*aw; -aw-const folded into D)
__global__ __launch_bounds__(256, 8) void sympnet_main(
    const float* __restrict__ x,
    const float* __restrict__ act_w,
    const float* __restrict__ bias_b,
    const float* __restrict__ lin_w,
    float* __restrict__ out)
{
    __shared__ float tab[NL * 16];

    // ---- per-block table build (threads 0..31, one layer each; ~60 flops) ----
    {
        int t = threadIdx.x;
        if (t < NL) {
            // Compose the 8 unit shears into M (det = 1).
            float m00 = 1.f, m01 = 0.f, m10 = 0.f, m11 = 1.f;
            #pragma unroll
            for (int j = 0; j < 8; ++j) {
                float w = lin_w[t * 8 + j];
                if ((j & 1) == 0) { m00 = fmaf(w, m10, m00); m01 = fmaf(w, m11, m01); }
                else              { m10 = fmaf(w, m00, m10); m11 = fmaf(w, m01, m11); }
            }
            float b0 = bias_b[2 * t], b1 = bias_b[2 * t + 1];
            float aw = act_w[t];
            const float c = C_SCALE;
            float awc = aw * c;

            // Forward: activation (tanh add, +awc folded forward through M), then
            // v <- M*(v + c*b).  C = c*M*b + awc*(M column of the activated coord).
            float C0 = c * fmaf(m00, b0, m01 * b1);
            float C1 = c * fmaf(m10, b0, m11 * b1);
            if ((t & 1) == 0) { C0 = fmaf(awc, m00, C0); C1 = fmaf(awc, m10, C1); }
            else              { C0 = fmaf(awc, m01, C0); C1 = fmaf(awc, m11, C1); }
            float* f = &tab[t * 16];
            f[0] = m00; f[1] = m01; f[2] = m10; f[3] = m11;
            f[4] = C0;  f[5] = C1;  f[6] = -2.f * awc; f[7] = 0.f;

            // Inverse: v <- Minv*v - c*b, then subtract activation (−awc in D).
            float i00 = m11, i01 = -m01, i10 = -m10, i11 = m00;
            float D0 = -c * b0, D1 = -c * b1;
            if ((t & 1) == 0) D0 -= awc; else D1 -= awc;
            // Fold time-reversal p <- -p into the FIRST inverse layer (t == NL-1):
            // Minv * diag(1,-1) negates the second column. Sign folds are exact.
            if (t == NL - 1) { i01 = -i01; i11 = -i11; }
            f[8]  = i00; f[9]  = i01; f[10] = i10; f[11] = i11;
            f[12] = D0;  f[13] = D1;  f[14] = 2.f * awc; f[15] = 0.f;
        }
    }
    __syncthreads();

    const float4* t4 = (const float4*)tab;   // uniform-address LDS broadcast reads

    int gid = blockIdx.x * blockDim.x + threadIdx.x;
    int nthreads = gridDim.x * blockDim.x;
    const float4* x4 = (const float4*)x;
    float4* out4 = (float4*)out;

    // Lane-consecutive layout: thread owns x4[gid] and x4[gid + nthreads]
    // -> every global load/store instruction is perfectly coalesced.
    float Q[PPT], P[PPT];
    {
        float4 v0 = x4[gid];
        float4 v1 = x4[gid + nthreads];
        Q[0] = C_SCALE * v0.x; P[0] = C_SCALE * v0.y;
        Q[1] = C_SCALE * v0.z; P[1] = C_SCALE * v0.w;
        Q[2] = C_SCALE * v1.x; P[2] = C_SCALE * v1.y;
        Q[3] = C_SCALE * v1.z; P[3] = C_SCALE * v1.w;
    }

    // ---------------- forward chain (2 layers / iter, tables double-buffered) ----------------
    {
        float4 fa = t4[0], fb = t4[1];       // even layer i   (act on q, tanh(p))
        float4 ga = t4[4], gb = t4[5];       // odd layer i+1  (act on p, tanh(q))
        #pragma unroll 1
        for (int i = 0; i < NL; i += 2) {
            int nx = (i + 2 < NL) ? (i + 2) : 0;          // wrapped prefetch (harmless)
            float4 nfa = t4[4 * nx],     nfb = t4[4 * nx + 1];
            float4 nga = t4[4 * nx + 4], ngb = t4[4 * nx + 5];
            #pragma unroll
            for (int k = 0; k < PPT; ++k) {
                float r  = __builtin_amdgcn_rcpf(fast_exp2(P[k]) + 1.0f);
                float Qa = fmaf(fb.z, r, Q[k]);
                float Qn = fmaf(fa.x, Qa, fmaf(fa.y, P[k], fb.x));
                float Pn = fmaf(fa.z, Qa, fmaf(fa.w, P[k], fb.y));
                float r2 = __builtin_amdgcn_rcpf(fast_exp2(Qn) + 1.0f);
                float Pa = fmaf(gb.z, r2, Pn);
                Q[k] = fmaf(ga.x, Qn, fmaf(ga.y, Pa, gb.x));
                P[k] = fmaf(ga.z, Qn, fmaf(ga.w, Pa, gb.y));
            }
            fa = nfa; fb = nfb; ga = nga; gb = ngb;
        }
    }

    // time reversal (P = -P) is folded into layer NL-1's inverse table.

    // ---------------- inverse chain (2 layers / iter, tables double-buffered) ----------------
    {
        int i = NL - 1;
        float4 ga = t4[4 * i + 2],       gb = t4[4 * i + 3];        // odd layer inverse
        float4 fa = t4[4 * (i - 1) + 2], fb = t4[4 * (i - 1) + 3];  // even layer inverse
        #pragma unroll 1
        for (; i > 0; i -= 2) {
            int nx = (i > 2) ? (i - 2) : (NL - 1);        // wrapped prefetch (harmless)
            float4 nga = t4[4 * nx + 2],       ngb = t4[4 * nx + 3];
            float4 nfa = t4[4 * (nx - 1) + 2], nfb = t4[4 * (nx - 1) + 3];
            #pragma unroll
            for (int k = 0; k < PPT; ++k) {
                float Qn = fmaf(ga.x, Q[k], fmaf(ga.y, P[k], gb.x));
                float Pn = fmaf(ga.z, Q[k], fmaf(ga.w, P[k], gb.y));
                float r  = __builtin_amdgcn_rcpf(fast_exp2(Qn) + 1.0f);
                Pn = fmaf(gb.z, r, Pn);
                float Q2 = fmaf(fa.x, Qn, fmaf(fa.y, Pn, fb.x));
                float P2 = fmaf(fa.z, Qn, fmaf(fa.w, Pn, fb.y));
                float r2 = __builtin_amdgcn_rcpf(fast_exp2(P2) + 1.0f);
                Q[k] = fmaf(fb.z, r2, Q2);
                P[k] = P2;
            }
            ga = nga; gb = ngb; fa = nfa; fb = nfb;
        }
    }

    // final scale [1, -1] and unscale by 1/c
    {
        float4 o0, o1;
        o0.x =  INV_C * Q[0];  o0.y = -INV_C * P[0];
        o0.z =  INV_C * Q[1];  o0.w = -INV_C * P[1];
        o1.x =  INV_C * Q[2];  o1.y = -INV_C * P[2];
        o1.z =  INV_C * Q[3];  o1.w = -INV_C * P[3];
        out4[gid] = o0;
        out4[gid + nthreads] = o1;
    }
}

extern "C" void kernel_launch(void* const* d_in, const int* in_sizes, int n_in,
                              void* d_out, int out_size, void* d_ws, size_t ws_size,
                              hipStream_t stream) {
    const float* x      = (const float*)d_in[0];
    const float* act_w  = (const float*)d_in[1];
    const float* bias_b = (const float*)d_in[2];
    const float* lin_w  = (const float*)d_in[3];
    float* out = (float*)d_out;
    (void)d_ws; (void)ws_size;   // workspace intentionally unused (avoid ws re-poison cost)

    int npts = in_sizes[0] / 2;                    // 2097152
    int nthreads = npts / PPT;                     // 524288
    int blocks = (nthreads + 255) / 256;           // 2048
    sympnet_main<<<blocks, 256, 0, stream>>>(x, act_w, bias_b, lin_w, out);
}